// Round 1
// baseline (3684.051 us; speedup 1.0000x reference)
//
#include <hip/hip_runtime.h>
#include <cstdint>
#include <cstddef>

// Transformer encoder fwd: B=8,S=1024,H=1024,NH=16,HD=64,PF=4096,L=6.
// Strategy: bf16 MFMA for all GEMMs (m97 128x128/BK=32 structure, global_load_lds),
// flash attention with swapped QK^T + shuffle P-relayout, f32 residual+LN.
// Workspace need: ~243 MB.

#define DI __device__ __forceinline__

typedef __attribute__((ext_vector_type(8))) short short8;
typedef __attribute__((ext_vector_type(4))) short s16x4;
typedef __attribute__((ext_vector_type(4))) float f32x4;
typedef __attribute__((ext_vector_type(4))) unsigned u32x4;

static constexpr int H  = 1024;
static constexpr int S  = 1024;
static constexpr int BB = 8;
static constexpr int NH = 16;
static constexpr int PF = 4096;
static constexpr int M  = BB * S;   // 8192 rows
static constexpr int L  = 6;

DI short f2bf(float f) {                       // RNE f32->bf16
  unsigned u = __builtin_bit_cast(unsigned, f);
  u += 0x7fffu + ((u >> 16) & 1u);
  return (short)(u >> 16);
}

DI void async16(void* lds, const void* g) {    // global->LDS direct, 16B/lane
  __builtin_amdgcn_global_load_lds(
      (const __attribute__((address_space(1))) unsigned*)g,
      (__attribute__((address_space(3))) unsigned*)lds, 16, 0, 0);
}

DI f32x4 mfma16(short8 a, short8 b, f32x4 c) {
  return __builtin_amdgcn_mfma_f32_16x16x32_bf16(a, b, c, 0, 0, 0);
}

// ---------------- embedding: x = tok[src]*32 + pos ----------------
__global__ __launch_bounds__(256) void embed_kernel(
    const int* __restrict__ src, const float* __restrict__ tok,
    const float* __restrict__ pos, float* __restrict__ xf,
    short* __restrict__ xb) {
  const int row = blockIdx.x;
  const int s = row & (S - 1);
  const int i0 = threadIdx.x << 2;
  const int v = src[row];
  const float4 te = *(const float4*)(tok + (size_t)v * H + i0);
  const float4 pe = *(const float4*)(pos + (size_t)s * H + i0);
  float o[4] = {te.x * 32.f + pe.x, te.y * 32.f + pe.y,
                te.z * 32.f + pe.z, te.w * 32.f + pe.w};
  *(float4*)(xf + (size_t)row * H + i0) = make_float4(o[0], o[1], o[2], o[3]);
  s16x4 pk;
  pk[0] = f2bf(o[0]); pk[1] = f2bf(o[1]); pk[2] = f2bf(o[2]); pk[3] = f2bf(o[3]);
  *(s16x4*)(xb + (size_t)row * H + i0) = pk;
}

// ------------- weight convert+transpose: W[K][N] f32 -> Wt[N][K] bf16 -------------
__global__ __launch_bounds__(256) void wconv_kernel(
    const float* __restrict__ W, short* __restrict__ Wt, int K, int N) {
  __shared__ float tile[64][65];
  const int ntn = N >> 6;
  const int k0 = (blockIdx.x / ntn) << 6;
  const int n0 = (blockIdx.x % ntn) << 6;
  const int r4 = threadIdx.x >> 6, cc = threadIdx.x & 63;
#pragma unroll
  for (int i = 0; i < 16; i++) {
    const int r = (i << 2) + r4;
    tile[r][cc] = W[(size_t)(k0 + r) * N + n0 + cc];
  }
  __syncthreads();
#pragma unroll
  for (int i = 0; i < 16; i++) {
    const int n = (i << 2) + r4;
    Wt[(size_t)(n0 + n) * K + k0 + cc] = f2bf(tile[cc][n]);
  }
}

// ---------------- GEMM: out = A[M,K]bf16 * Wt[N,K]^T + bias ----------------
// EPI 0: bf16   1: bf16+relu   2: f32   3: bf16 transposed store into vt[B][H][S]
template <int EPI>
__global__ __launch_bounds__(256) void gemm_bf16(
    const short* __restrict__ A, const short* __restrict__ Bt,
    const float* __restrict__ bias, void* __restrict__ out,
    const int nbn, const int K) {
  __shared__ short lsa[128 * 32];
  __shared__ short lsb[128 * 32];
  const int tid = threadIdx.x;
  const int w = tid >> 6, lane = tid & 63;
  const int g = lane >> 4, ci = lane & 15;
  const int wr = w >> 1, wc = w & 1;
  const int brow = (blockIdx.x / nbn) << 7;
  const int bcol = (blockIdx.x % nbn) << 7;

  const f32x4 zero = {0.f, 0.f, 0.f, 0.f};
  f32x4 acc[4][4];
#pragma unroll
  for (int i = 0; i < 4; i++)
#pragma unroll
    for (int j = 0; j < 4; j++) acc[i][j] = zero;

  const int c0 = tid, c1 = tid + 256;
  const short* a0 = A + (size_t)(brow + (c0 >> 2)) * K + ((c0 & 3) << 3);
  const short* a1 = A + (size_t)(brow + (c1 >> 2)) * K + ((c1 & 3) << 3);
  const short* b0 = Bt + (size_t)(bcol + (c0 >> 2)) * K + ((c0 & 3) << 3);
  const short* b1 = Bt + (size_t)(bcol + (c1 >> 2)) * K + ((c1 & 3) << 3);
  short* la0 = lsa + (w << 6) * 8;           // wave-uniform LDS bases
  short* la1 = lsa + (256 + (w << 6)) * 8;
  short* lb0 = lsb + (w << 6) * 8;
  short* lb1 = lsb + (256 + (w << 6)) * 8;

  const short* pa = lsa + ((wr << 6) + ci) * 32 + (g << 3);
  const short* pb = lsb + ((wc << 6) + ci) * 32 + (g << 3);

  for (int k0 = 0; k0 < K; k0 += 32) {
    async16(la0, a0 + k0);
    async16(la1, a1 + k0);
    async16(lb0, b0 + k0);
    async16(lb1, b1 + k0);
    __syncthreads();                         // drains vmcnt -> tiles ready
    short8 af[4], bfr[4];
#pragma unroll
    for (int mi = 0; mi < 4; mi++) af[mi] = *(const short8*)(pa + mi * 16 * 32);
#pragma unroll
    for (int ni = 0; ni < 4; ni++) bfr[ni] = *(const short8*)(pb + ni * 16 * 32);
#pragma unroll
    for (int mi = 0; mi < 4; mi++)
#pragma unroll
      for (int ni = 0; ni < 4; ni++)
        acc[mi][ni] = mfma16(af[mi], bfr[ni], acc[mi][ni]);
    __syncthreads();                         // all reads done before next stage
  }

  const int N = nbn << 7;
#pragma unroll
  for (int ni = 0; ni < 4; ni++) {
    const int col = bcol + (wc << 6) + (ni << 4) + ci;
    const float bv = bias[col];
#pragma unroll
    for (int mi = 0; mi < 4; mi++) {
      const int row0 = brow + (wr << 6) + (mi << 4) + (g << 2);
      if constexpr (EPI == 0 || EPI == 1) {
        short* o = (short*)out;
#pragma unroll
        for (int r = 0; r < 4; r++) {
          float vv = acc[mi][ni][r] + bv;
          if constexpr (EPI == 1) vv = fmaxf(vv, 0.f);
          o[(size_t)(row0 + r) * N + col] = f2bf(vv);
        }
      } else if constexpr (EPI == 2) {
        float* o = (float*)out;
#pragma unroll
        for (int r = 0; r < 4; r++)
          o[(size_t)(row0 + r) * N + col] = acc[mi][ni][r] + bv;
      } else {  // vt[b][n][s] transposed bf16 store (4 consecutive s -> 8B)
        short* o = (short*)out;
        const int bidx = row0 >> 10, s0 = row0 & (S - 1);
        s16x4 pk;
#pragma unroll
        for (int r = 0; r < 4; r++) pk[r] = f2bf(acc[mi][ni][r] + bv);
        *(s16x4*)(o + ((size_t)bidx * H + col) * S + s0) = pk;
      }
    }
  }
}

// ---------------- flash attention ----------------
// grid: B*NH*(S/64) blocks, 4 waves; wave handles 16 queries, loops 16 k-tiles of 64.
// Swapped QK^T: st = mfma(K_frag, Q_frag) -> lane owns query ci, 16 scores/lane.
__global__ __launch_bounds__(256) void attn_kernel(
    const short* __restrict__ q, const short* __restrict__ k,
    const short* __restrict__ vt, short* __restrict__ ao) {
  const int tid = threadIdx.x;
  const int w = tid >> 6, lane = tid & 63;
  const int g = lane >> 4, ci = lane & 15;
  const int qt = blockIdx.x & 15;
  const int bh = blockIdx.x >> 4;
  const int b = bh >> 4, h = bh & 15;
  const int hbase = h << 6;

  const size_t qrow = (size_t)b * S + qt * 64 + w * 16 + ci;
  short8 qf[2];
#pragma unroll
  for (int ks = 0; ks < 2; ks++)
    qf[ks] = *(const short8*)(q + qrow * H + hbase + ks * 32 + (g << 3));

  const f32x4 zero = {0.f, 0.f, 0.f, 0.f};
  f32x4 of[4];
#pragma unroll
  for (int nf = 0; nf < 4; nf++) of[nf] = zero;
  float mrun = -INFINITY, lsum = 0.f;

  const short* kp = k + ((size_t)b * S) * H + hbase;
  const short* vp = vt + ((size_t)b * H + hbase) * S;

  for (int kt = 0; kt < 16; kt++) {
    const int kr0 = kt << 6;
    f32x4 st[4];
#pragma unroll
    for (int mf = 0; mf < 4; mf++) st[mf] = zero;
#pragma unroll
    for (int ks = 0; ks < 2; ks++) {
#pragma unroll
      for (int mf = 0; mf < 4; mf++) {
        const short8 kf = *(const short8*)(kp + (size_t)(kr0 + (mf << 4) + ci) * H +
                                           ks * 32 + (g << 3));
        st[mf] = mfma16(kf, qf[ks], st[mf]);   // st = K * Q^T  (S^T tile)
      }
    }
    // per-lane softmax for query ci (values replicated across 4 lane groups)
    float tmax = -INFINITY;
#pragma unroll
    for (int mf = 0; mf < 4; mf++)
#pragma unroll
      for (int r = 0; r < 4; r++) tmax = fmaxf(tmax, st[mf][r]);
    tmax = fmaxf(tmax, __shfl_xor(tmax, 16));
    tmax = fmaxf(tmax, __shfl_xor(tmax, 32));
    const float mnew = fmaxf(mrun, tmax * 0.125f);
    const float alpha = __expf(mrun - mnew);
    float p[4][4];
    float rs = 0.f;
#pragma unroll
    for (int mf = 0; mf < 4; mf++)
#pragma unroll
      for (int r = 0; r < 4; r++) {
        p[mf][r] = __expf(st[mf][r] * 0.125f - mnew);
        rs += p[mf][r];
      }
    rs += __shfl_xor(rs, 16);
    rs += __shfl_xor(rs, 32);
    lsum = lsum * alpha + rs;
    mrun = mnew;

    unsigned plo[4], phi[4];                  // P packed to bf16 pairs
#pragma unroll
    for (int mf = 0; mf < 4; mf++) {
      plo[mf] = (unsigned)(unsigned short)f2bf(p[mf][0]) |
                ((unsigned)(unsigned short)f2bf(p[mf][1]) << 16);
      phi[mf] = (unsigned)(unsigned short)f2bf(p[mf][2]) |
                ((unsigned)(unsigned short)f2bf(p[mf][3]) << 16);
    }
    // rescale O (O rows indexed by q = g*4+r; alpha lives at lane q)
#pragma unroll
    for (int r = 0; r < 4; r++) {
      const float av = __shfl(alpha, (g << 2) + r);
#pragma unroll
      for (int nf = 0; nf < 4; nf++) of[nf][r] *= av;
    }
    // relayout P^T (C-layout) -> P (A-layout) via 16 bpermutes, then PV
    const int srcA = ci + ((g & 1) << 5);
    const int srcB = srcA + 16;
    const bool hi = (g >> 1) != 0;
#pragma unroll
    for (int ks = 0; ks < 2; ks++) {
      const unsigned ua0 = (unsigned)__shfl((int)plo[2 * ks], srcA);
      const unsigned ub0 = (unsigned)__shfl((int)plo[2 * ks + 1], srcA);
      const unsigned ua1 = (unsigned)__shfl((int)phi[2 * ks], srcA);
      const unsigned ub1 = (unsigned)__shfl((int)phi[2 * ks + 1], srcA);
      const unsigned ua2 = (unsigned)__shfl((int)plo[2 * ks], srcB);
      const unsigned ub2 = (unsigned)__shfl((int)plo[2 * ks + 1], srcB);
      const unsigned ua3 = (unsigned)__shfl((int)phi[2 * ks], srcB);
      const unsigned ub3 = (unsigned)__shfl((int)phi[2 * ks + 1], srcB);
      u32x4 uu;
      uu[0] = hi ? ub0 : ua0;
      uu[1] = hi ? ub1 : ua1;
      uu[2] = hi ? ub2 : ua2;
      uu[3] = hi ? ub3 : ua3;
      const short8 pafrag = __builtin_bit_cast(short8, uu);
#pragma unroll
      for (int nf = 0; nf < 4; nf++) {
        const short8 vfr = *(const short8*)(vp + (size_t)((nf << 4) + ci) * S +
                                            kr0 + ks * 32 + (g << 3));
        of[nf] = mfma16(pafrag, vfr, of[nf]);
      }
    }
  }
#pragma unroll
  for (int r = 0; r < 4; r++) {
    const float ls = __shfl(lsum, (g << 2) + r);
    const float inv = 1.f / ls;
    const size_t orow = (size_t)b * S + qt * 64 + w * 16 + (g << 2) + r;
#pragma unroll
    for (int nf = 0; nf < 4; nf++)
      ao[orow * H + hbase + (nf << 4) + ci] = f2bf(of[nf][r] * inv);
  }
}

// ---------------- residual + layernorm ----------------
__global__ __launch_bounds__(256) void ln_kernel(
    const float* __restrict__ x, const float* __restrict__ t,
    const float* __restrict__ gm, const float* __restrict__ bt,
    float* __restrict__ yf, short* __restrict__ yb) {
  const int row = blockIdx.x;
  const int i0 = threadIdx.x << 2;
  const size_t base = (size_t)row * H + i0;
  const float4 a = *(const float4*)(x + base);
  const float4 bb = *(const float4*)(t + base);
  float v[4] = {a.x + bb.x, a.y + bb.y, a.z + bb.z, a.w + bb.w};
  float s = v[0] + v[1] + v[2] + v[3];
  float qq = v[0] * v[0] + v[1] * v[1] + v[2] * v[2] + v[3] * v[3];
#pragma unroll
  for (int off = 32; off; off >>= 1) {
    s += __shfl_down(s, off);
    qq += __shfl_down(qq, off);
  }
  __shared__ float red[8];
  const int w = threadIdx.x >> 6, lane = threadIdx.x & 63;
  if (lane == 0) { red[w] = s; red[4 + w] = qq; }
  __syncthreads();
  s = red[0] + red[1] + red[2] + red[3];
  qq = red[4] + red[5] + red[6] + red[7];
  const float mean = s * (1.f / H);
  float var = qq * (1.f / H) - mean * mean;
  var = fmaxf(var, 0.f);
  const float rstd = rsqrtf(var + 1e-5f);
  const float4 gv = *(const float4*)(gm + i0);
  const float4 bv = *(const float4*)(bt + i0);
  float y[4] = {(v[0] - mean) * rstd * gv.x + bv.x,
                (v[1] - mean) * rstd * gv.y + bv.y,
                (v[2] - mean) * rstd * gv.z + bv.z,
                (v[3] - mean) * rstd * gv.w + bv.w};
  *(float4*)(yf + base) = make_float4(y[0], y[1], y[2], y[3]);
  s16x4 pk;
  pk[0] = f2bf(y[0]); pk[1] = f2bf(y[1]); pk[2] = f2bf(y[2]); pk[3] = f2bf(y[3]);
  *(s16x4*)(yb + base) = pk;
}

// ---------------- host ----------------
extern "C" void kernel_launch(void* const* d_in, const int* in_sizes, int n_in,
                              void* d_out, int out_size, void* d_ws, size_t ws_size,
                              hipStream_t stream) {
  const int* src = (const int*)d_in[0];
  // d_in[1] = src_mask: all-true -> masking is identity, skipped.
  const float* tok = (const float*)d_in[2];
  const float* pos = (const float*)d_in[3];
  const float* Wq = (const float*)d_in[4];
  const float* bq = (const float*)d_in[5];
  const float* Wk = (const float*)d_in[6];
  const float* bk = (const float*)d_in[7];
  const float* Wv = (const float*)d_in[8];
  const float* bv = (const float*)d_in[9];
  const float* Wo = (const float*)d_in[10];
  const float* bo = (const float*)d_in[11];
  const float* W1 = (const float*)d_in[12];
  const float* b1 = (const float*)d_in[13];
  const float* W2 = (const float*)d_in[14];
  const float* b2 = (const float*)d_in[15];
  const float* g1 = (const float*)d_in[16];
  const float* be1 = (const float*)d_in[17];
  const float* g2 = (const float*)d_in[18];
  const float* be2 = (const float*)d_in[19];

  char* p = (char*)d_ws;
  auto take = [&](size_t bytes) {
    char* r = p;
    p += (bytes + 255) & ~(size_t)255;
    return r;
  };
  float* xf   = (float*)take((size_t)M * H * 4);
  short* xb   = (short*)take((size_t)M * H * 2);
  float* tmp  = (float*)take((size_t)M * H * 4);
  short* qb   = (short*)take((size_t)M * H * 2);
  short* kbuf = (short*)take((size_t)M * H * 2);
  short* vtb  = (short*)take((size_t)M * H * 2);
  short* aob  = (short*)take((size_t)M * H * 2);
  short* fb   = (short*)take((size_t)M * PF * 2);
  short* wtq  = (short*)take((size_t)H * H * 2);
  short* wtk  = (short*)take((size_t)H * H * 2);
  short* wtv  = (short*)take((size_t)H * H * 2);
  short* wto  = (short*)take((size_t)H * H * 2);
  short* wt1  = (short*)take((size_t)H * PF * 2);
  short* wt2  = (short*)take((size_t)H * PF * 2);

  embed_kernel<<<M, 256, 0, stream>>>(src, tok, pos, xf, xb);

  for (int l = 0; l < L; l++) {
    wconv_kernel<<<(H / 64) * (H / 64), 256, 0, stream>>>(Wq + (size_t)l * H * H, wtq, H, H);
    wconv_kernel<<<(H / 64) * (H / 64), 256, 0, stream>>>(Wk + (size_t)l * H * H, wtk, H, H);
    wconv_kernel<<<(H / 64) * (H / 64), 256, 0, stream>>>(Wv + (size_t)l * H * H, wtv, H, H);
    wconv_kernel<<<(H / 64) * (H / 64), 256, 0, stream>>>(Wo + (size_t)l * H * H, wto, H, H);
    wconv_kernel<<<(H / 64) * (PF / 64), 256, 0, stream>>>(W1 + (size_t)l * H * PF, wt1, H, PF);
    wconv_kernel<<<(PF / 64) * (H / 64), 256, 0, stream>>>(W2 + (size_t)l * PF * H, wt2, PF, H);

    gemm_bf16<0><<<(M / 128) * (H / 128), 256, 0, stream>>>(xb, wtq, bq + (size_t)l * H, qb, H / 128, H);
    gemm_bf16<0><<<(M / 128) * (H / 128), 256, 0, stream>>>(xb, wtk, bk + (size_t)l * H, kbuf, H / 128, H);
    gemm_bf16<3><<<(M / 128) * (H / 128), 256, 0, stream>>>(xb, wtv, bv + (size_t)l * H, vtb, H / 128, H);
    attn_kernel<<<BB * NH * (S / 64), 256, 0, stream>>>(qb, kbuf, vtb, aob);
    gemm_bf16<2><<<(M / 128) * (H / 128), 256, 0, stream>>>(aob, wto, bo + (size_t)l * H, tmp, H / 128, H);
    ln_kernel<<<M, 256, 0, stream>>>(xf, tmp, g1 + (size_t)l * H, be1 + (size_t)l * H, xf, xb);
    gemm_bf16<1><<<(M / 128) * (PF / 128), 256, 0, stream>>>(xb, wt1, b1 + (size_t)l * PF, fb, PF / 128, H);
    gemm_bf16<2><<<(M / 128) * (H / 128), 256, 0, stream>>>(fb, wt2, b2 + (size_t)l * H, tmp, H / 128, PF);
    float* yf = (l == L - 1) ? (float*)d_out : xf;
    ln_kernel<<<M, 256, 0, stream>>>(xf, tmp, g2 + (size_t)l * H, be2 + (size_t)l * H, yf, xb);
  }
}

// Round 2
// 2769.719 us; speedup vs baseline: 1.3301x; 1.3301x over previous
//
#include <hip/hip_runtime.h>
#include <cstdint>
#include <cstddef>

// Transformer encoder fwd: B=8,S=1024,H=1024,NH=16,HD=64,PF=4096,L=6.
// R2: attention rewritten — LDS-staged K/V^T (double-buffered, XOR-swizzled via
// pre-swizzled global_load_lds source), O^T-form PV with in-lane P fragments
// (zero relayout shuffles), per-lane softmax state.

#define DI __device__ __forceinline__

typedef __attribute__((ext_vector_type(8))) short short8;
typedef __attribute__((ext_vector_type(4))) short s16x4;
typedef __attribute__((ext_vector_type(4))) float f32x4;
typedef __attribute__((ext_vector_type(4))) unsigned u32x4;

static constexpr int H  = 1024;
static constexpr int S  = 1024;
static constexpr int BB = 8;
static constexpr int NH = 16;
static constexpr int PF = 4096;
static constexpr int M  = BB * S;   // 8192 rows
static constexpr int L  = 6;

DI short f2bf(float f) {                       // RNE f32->bf16
  unsigned u = __builtin_bit_cast(unsigned, f);
  u += 0x7fffu + ((u >> 16) & 1u);
  return (short)(u >> 16);
}

DI unsigned packbf(float a, float b) {         // truncating bf16 pair pack
  return (__builtin_bit_cast(unsigned, a) >> 16) |
         (__builtin_bit_cast(unsigned, b) & 0xffff0000u);
}

DI void async16(void* lds, const void* g) {    // global->LDS direct, 16B/lane
  __builtin_amdgcn_global_load_lds(
      (const __attribute__((address_space(1))) unsigned*)g,
      (__attribute__((address_space(3))) unsigned*)lds, 16, 0, 0);
}

DI f32x4 mfma16(short8 a, short8 b, f32x4 c) {
  return __builtin_amdgcn_mfma_f32_16x16x32_bf16(a, b, c, 0, 0, 0);
}

// ---------------- embedding: x = tok[src]*32 + pos ----------------
__global__ __launch_bounds__(256) void embed_kernel(
    const int* __restrict__ src, const float* __restrict__ tok,
    const float* __restrict__ pos, float* __restrict__ xf,
    short* __restrict__ xb) {
  const int row = blockIdx.x;
  const int s = row & (S - 1);
  const int i0 = threadIdx.x << 2;
  const int v = src[row];
  const float4 te = *(const float4*)(tok + (size_t)v * H + i0);
  const float4 pe = *(const float4*)(pos + (size_t)s * H + i0);
  float o[4] = {te.x * 32.f + pe.x, te.y * 32.f + pe.y,
                te.z * 32.f + pe.z, te.w * 32.f + pe.w};
  *(float4*)(xf + (size_t)row * H + i0) = make_float4(o[0], o[1], o[2], o[3]);
  s16x4 pk;
  pk[0] = f2bf(o[0]); pk[1] = f2bf(o[1]); pk[2] = f2bf(o[2]); pk[3] = f2bf(o[3]);
  *(s16x4*)(xb + (size_t)row * H + i0) = pk;
}

// ------------- weight convert+transpose: W[K][N] f32 -> Wt[N][K] bf16 -------------
__global__ __launch_bounds__(256) void wconv_kernel(
    const float* __restrict__ W, short* __restrict__ Wt, int K, int N) {
  __shared__ float tile[64][65];
  const int ntn = N >> 6;
  const int k0 = (blockIdx.x / ntn) << 6;
  const int n0 = (blockIdx.x % ntn) << 6;
  const int r4 = threadIdx.x >> 6, cc = threadIdx.x & 63;
#pragma unroll
  for (int i = 0; i < 16; i++) {
    const int r = (i << 2) + r4;
    tile[r][cc] = W[(size_t)(k0 + r) * N + n0 + cc];
  }
  __syncthreads();
#pragma unroll
  for (int i = 0; i < 16; i++) {
    const int n = (i << 2) + r4;
    Wt[(size_t)(n0 + n) * K + k0 + cc] = f2bf(tile[cc][n]);
  }
}

// ---------------- GEMM: out = A[M,K]bf16 * Wt[N,K]^T + bias ----------------
// EPI 0: bf16   1: bf16+relu   2: f32   3: bf16 transposed store into vt[B][H][S]
template <int EPI>
__global__ __launch_bounds__(256) void gemm_bf16(
    const short* __restrict__ A, const short* __restrict__ Bt,
    const float* __restrict__ bias, void* __restrict__ out,
    const int nbn, const int K) {
  __shared__ short lsa[128 * 32];
  __shared__ short lsb[128 * 32];
  const int tid = threadIdx.x;
  const int w = tid >> 6, lane = tid & 63;
  const int g = lane >> 4, ci = lane & 15;
  const int wr = w >> 1, wc = w & 1;
  const int brow = (blockIdx.x / nbn) << 7;
  const int bcol = (blockIdx.x % nbn) << 7;

  const f32x4 zero = {0.f, 0.f, 0.f, 0.f};
  f32x4 acc[4][4];
#pragma unroll
  for (int i = 0; i < 4; i++)
#pragma unroll
    for (int j = 0; j < 4; j++) acc[i][j] = zero;

  const int c0 = tid, c1 = tid + 256;
  const short* a0 = A + (size_t)(brow + (c0 >> 2)) * K + ((c0 & 3) << 3);
  const short* a1 = A + (size_t)(brow + (c1 >> 2)) * K + ((c1 & 3) << 3);
  const short* b0 = Bt + (size_t)(bcol + (c0 >> 2)) * K + ((c0 & 3) << 3);
  const short* b1 = Bt + (size_t)(bcol + (c1 >> 2)) * K + ((c1 & 3) << 3);
  short* la0 = lsa + (w << 6) * 8;           // wave-uniform LDS bases
  short* la1 = lsa + (256 + (w << 6)) * 8;
  short* lb0 = lsb + (w << 6) * 8;
  short* lb1 = lsb + (256 + (w << 6)) * 8;

  const short* pa = lsa + ((wr << 6) + ci) * 32 + (g << 3);
  const short* pb = lsb + ((wc << 6) + ci) * 32 + (g << 3);

  for (int k0 = 0; k0 < K; k0 += 32) {
    async16(la0, a0 + k0);
    async16(la1, a1 + k0);
    async16(lb0, b0 + k0);
    async16(lb1, b1 + k0);
    __syncthreads();                         // drains vmcnt -> tiles ready
    short8 af[4], bfr[4];
#pragma unroll
    for (int mi = 0; mi < 4; mi++) af[mi] = *(const short8*)(pa + mi * 16 * 32);
#pragma unroll
    for (int ni = 0; ni < 4; ni++) bfr[ni] = *(const short8*)(pb + ni * 16 * 32);
#pragma unroll
    for (int mi = 0; mi < 4; mi++)
#pragma unroll
      for (int ni = 0; ni < 4; ni++)
        acc[mi][ni] = mfma16(af[mi], bfr[ni], acc[mi][ni]);
    __syncthreads();                         // all reads done before next stage
  }

  const int N = nbn << 7;
#pragma unroll
  for (int ni = 0; ni < 4; ni++) {
    const int col = bcol + (wc << 6) + (ni << 4) + ci;
    const float bv = bias[col];
#pragma unroll
    for (int mi = 0; mi < 4; mi++) {
      const int row0 = brow + (wr << 6) + (mi << 4) + (g << 2);
      if constexpr (EPI == 0 || EPI == 1) {
        short* o = (short*)out;
#pragma unroll
        for (int r = 0; r < 4; r++) {
          float vv = acc[mi][ni][r] + bv;
          if constexpr (EPI == 1) vv = fmaxf(vv, 0.f);
          o[(size_t)(row0 + r) * N + col] = f2bf(vv);
        }
      } else if constexpr (EPI == 2) {
        float* o = (float*)out;
#pragma unroll
        for (int r = 0; r < 4; r++)
          o[(size_t)(row0 + r) * N + col] = acc[mi][ni][r] + bv;
      } else {  // vt[b][n][s] transposed bf16 store (4 consecutive s -> 8B)
        short* o = (short*)out;
        const int bidx = row0 >> 10, s0 = row0 & (S - 1);
        s16x4 pk;
#pragma unroll
        for (int r = 0; r < 4; r++) pk[r] = f2bf(acc[mi][ni][r] + bv);
        *(s16x4*)(o + ((size_t)bidx * H + col) * S + s0) = pk;
      }
    }
  }
}

// ---------------- flash attention (R2) ----------------
// grid: B*NH*(S/64) blocks (XCD-swizzled), 4 waves; wave owns 16 queries.
// K-tile [64 keys][64 d] and V^T-tile [64 d][64 s] staged in LDS, double-buffered,
// XOR-swizzled (chunk ^= row&7) via pre-swizzled global_load_lds source.
// QK^T swapped (st = K*Q^T): lane (g,ci) holds P^T[key=mf*16+g*4+r][q=ci].
// PV in O^T form: O^T = mfma(V^T_frag, P^T_frag) with key bijection
// k_local(ks,g,e) = 16*(2ks+(e>>2)) + 4g + (e&3)  ->  B-frag is the lane's OWN
// packed p values (zero shuffles); A-frag = two ds_read_b64 of V^T.
__global__ __launch_bounds__(256) void attn_kernel(
    const short* __restrict__ q, const short* __restrict__ k,
    const short* __restrict__ vt, short* __restrict__ ao) {
  __shared__ short lsk[2][4096];
  __shared__ short lsv[2][4096];
  const int tid = threadIdx.x;
  const int w = tid >> 6, lane = tid & 63;
  const int g = lane >> 4, ci = lane & 15;
  const int bid = ((int)blockIdx.x & 7) * 256 + ((int)blockIdx.x >> 3);
  const int qt = bid & 15;
  const int bh = bid >> 4;
  const int b = bh >> 4, h = bh & 15;
  const int hbase = h << 6;

  // staging lane constants: row-within-8 = lane>>3, chunk = lane&7, src pre-swizzled
  const int r8 = lane >> 3, c8 = lane & 7;
  const int cs = c8 ^ r8;                      // source chunk (involution)
  const short* kbase = k + ((size_t)b * S) * H + hbase;    // [S][H] slice
  const short* vbase = vt + ((size_t)b * H + hbase) * S;   // [64 d][S] slice

  const size_t qrow = (size_t)b * S + (qt << 6) + (w << 4) + ci;
  short8 qf[2];
#pragma unroll
  for (int ks = 0; ks < 2; ks++)
    qf[ks] = *(const short8*)(q + qrow * H + hbase + ks * 32 + (g << 3));

  // LDS read byte offsets (swizzled): chunk ^= (row&7) = ci&7
  const int swz = ci & 7;
  int koff[2], voff[2][2];
#pragma unroll
  for (int ks = 0; ks < 2; ks++) {
    koff[ks] = ci * 128 + (((4 * ks + g) ^ swz) << 4);
#pragma unroll
    for (int pc = 0; pc < 2; pc++)
      voff[ks][pc] =
          ci * 128 + (((4 * ks + 2 * pc + (g >> 1)) ^ swz) << 4) + ((g & 1) << 3);
  }

  // prologue: stage tile 0 into buffer 0
#pragma unroll
  for (int t = 0; t < 2; t++) {
    const int row = (w << 3) + t * 32 + r8;
    async16(&lsk[0][t * 2048 + (w << 9)], kbase + (size_t)row * H + cs * 8);
    async16(&lsv[0][t * 2048 + (w << 9)], vbase + (size_t)row * S + cs * 8);
  }
  __syncthreads();

  const f32x4 zero = {0.f, 0.f, 0.f, 0.f};
  f32x4 of[4];
#pragma unroll
  for (int nf = 0; nf < 4; nf++) of[nf] = zero;
  float mrun = -INFINITY, lsum = 0.f;

#pragma unroll 2
  for (int kt = 0; kt < 16; kt++) {
    const int cur = kt & 1;
    if (kt < 15) {                            // prefetch next tile
      const int kr1 = (kt + 1) << 6;
#pragma unroll
      for (int t = 0; t < 2; t++) {
        const int row = (w << 3) + t * 32 + r8;
        async16(&lsk[cur ^ 1][t * 2048 + (w << 9)],
                kbase + (size_t)(kr1 + row) * H + cs * 8);
        async16(&lsv[cur ^ 1][t * 2048 + (w << 9)],
                vbase + (size_t)row * S + kr1 + cs * 8);
      }
    }
    const char* kb = (const char*)lsk[cur];
    const char* vb = (const char*)lsv[cur];

    // QK^T: st[mf] = P^T scores, keys mf*16+g*4+r, query ci
    f32x4 st[4];
#pragma unroll
    for (int mf = 0; mf < 4; mf++) st[mf] = zero;
#pragma unroll
    for (int ks = 0; ks < 2; ks++)
#pragma unroll
      for (int mf = 0; mf < 4; mf++) {
        const short8 kf = *(const short8*)(kb + koff[ks] + mf * 2048);
        st[mf] = mfma16(kf, qf[ks], st[mf]);
      }

    // online softmax, per-lane state for query ci (replicated over g)
    float tmax = -INFINITY;
#pragma unroll
    for (int mf = 0; mf < 4; mf++)
#pragma unroll
      for (int r = 0; r < 4; r++) tmax = fmaxf(tmax, st[mf][r]);
    tmax = fmaxf(tmax, __shfl_xor(tmax, 16));
    tmax = fmaxf(tmax, __shfl_xor(tmax, 32));
    const float mnew = fmaxf(mrun, tmax * 0.125f);
    const float alpha = __expf(mrun - mnew);
    float rs = 0.f;
    float p[4][4];
#pragma unroll
    for (int mf = 0; mf < 4; mf++)
#pragma unroll
      for (int r = 0; r < 4; r++) {
        p[mf][r] = __expf(__builtin_fmaf(st[mf][r], 0.125f, -mnew));
        rs += p[mf][r];
      }
    rs += __shfl_xor(rs, 16);
    rs += __shfl_xor(rs, 32);
    lsum = lsum * alpha + rs;
    mrun = mnew;

    unsigned pk[4][2];                        // packed bf16 pairs (truncated)
#pragma unroll
    for (int mf = 0; mf < 4; mf++) {
      pk[mf][0] = packbf(p[mf][0], p[mf][1]);
      pk[mf][1] = packbf(p[mf][2], p[mf][3]);
    }
#pragma unroll
    for (int nf = 0; nf < 4; nf++)
#pragma unroll
      for (int r = 0; r < 4; r++) of[nf][r] *= alpha;

    // PV: O^T[d=nf*16+g*4+r][q=ci] += V^T x P^T  (in-lane B fragments)
#pragma unroll
    for (int ks = 0; ks < 2; ks++) {
      u32x4 uu;
      uu[0] = pk[2 * ks][0];
      uu[1] = pk[2 * ks][1];
      uu[2] = pk[2 * ks + 1][0];
      uu[3] = pk[2 * ks + 1][1];
      const short8 pfrag = __builtin_bit_cast(short8, uu);
#pragma unroll
      for (int nf = 0; nf < 4; nf++) {
        union { short8 v8; s16x4 h[2]; } vv;
        vv.h[0] = *(const s16x4*)(vb + voff[ks][0] + nf * 2048);
        vv.h[1] = *(const s16x4*)(vb + voff[ks][1] + nf * 2048);
        of[nf] = mfma16(vv.v8, pfrag, of[nf]);
      }
    }
    __syncthreads();                          // next tile staged + reads done
  }

  const float inv = 1.f / lsum;               // per-lane (query ci)
#pragma unroll
  for (int nf = 0; nf < 4; nf++) {
    s16x4 o4;
#pragma unroll
    for (int r = 0; r < 4; r++) o4[r] = f2bf(of[nf][r] * inv);
    *(s16x4*)(ao + qrow * H + hbase + (nf << 4) + (g << 2)) = o4;
  }
}

// ---------------- residual + layernorm ----------------
__global__ __launch_bounds__(256) void ln_kernel(
    const float* __restrict__ x, const float* __restrict__ t,
    const float* __restrict__ gm, const float* __restrict__ bt,
    float* __restrict__ yf, short* __restrict__ yb) {
  const int row = blockIdx.x;
  const int i0 = threadIdx.x << 2;
  const size_t base = (size_t)row * H + i0;
  const float4 a = *(const float4*)(x + base);
  const float4 bb = *(const float4*)(t + base);
  float v[4] = {a.x + bb.x, a.y + bb.y, a.z + bb.z, a.w + bb.w};
  float s = v[0] + v[1] + v[2] + v[3];
  float qq = v[0] * v[0] + v[1] * v[1] + v[2] * v[2] + v[3] * v[3];
#pragma unroll
  for (int off = 32; off; off >>= 1) {
    s += __shfl_down(s, off);
    qq += __shfl_down(qq, off);
  }
  __shared__ float red[8];
  const int w = threadIdx.x >> 6, lane = threadIdx.x & 63;
  if (lane == 0) { red[w] = s; red[4 + w] = qq; }
  __syncthreads();
  s = red[0] + red[1] + red[2] + red[3];
  qq = red[4] + red[5] + red[6] + red[7];
  const float mean = s * (1.f / H);
  float var = qq * (1.f / H) - mean * mean;
  var = fmaxf(var, 0.f);
  const float rstd = rsqrtf(var + 1e-5f);
  const float4 gv = *(const float4*)(gm + i0);
  const float4 bv = *(const float4*)(bt + i0);
  float y[4] = {(v[0] - mean) * rstd * gv.x + bv.x,
                (v[1] - mean) * rstd * gv.y + bv.y,
                (v[2] - mean) * rstd * gv.z + bv.z,
                (v[3] - mean) * rstd * gv.w + bv.w};
  *(float4*)(yf + base) = make_float4(y[0], y[1], y[2], y[3]);
  s16x4 pk;
  pk[0] = f2bf(y[0]); pk[1] = f2bf(y[1]); pk[2] = f2bf(y[2]); pk[3] = f2bf(y[3]);
  *(s16x4*)(yb + base) = pk;
}

// ---------------- host ----------------
extern "C" void kernel_launch(void* const* d_in, const int* in_sizes, int n_in,
                              void* d_out, int out_size, void* d_ws, size_t ws_size,
                              hipStream_t stream) {
  const int* src = (const int*)d_in[0];
  // d_in[1] = src_mask: all-true -> masking is identity, skipped.
  const float* tok = (const float*)d_in[2];
  const float* pos = (const float*)d_in[3];
  const float* Wq = (const float*)d_in[4];
  const float* bq = (const float*)d_in[5];
  const float* Wk = (const float*)d_in[6];
  const float* bk = (const float*)d_in[7];
  const float* Wv = (const float*)d_in[8];
  const float* bv = (const float*)d_in[9];
  const float* Wo = (const float*)d_in[10];
  const float* bo = (const float*)d_in[11];
  const float* W1 = (const float*)d_in[12];
  const float* b1 = (const float*)d_in[13];
  const float* W2 = (const float*)d_in[14];
  const float* b2 = (const float*)d_in[15];
  const float* g1 = (const float*)d_in[16];
  const float* be1 = (const float*)d_in[17];
  const float* g2 = (const float*)d_in[18];
  const float* be2 = (const float*)d_in[19];

  char* p = (char*)d_ws;
  auto take = [&](size_t bytes) {
    char* r = p;
    p += (bytes + 255) & ~(size_t)255;
    return r;
  };
  float* xf   = (float*)take((size_t)M * H * 4);
  short* xb   = (short*)take((size_t)M * H * 2);
  float* tmp  = (float*)take((size_t)M * H * 4);
  short* qb   = (short*)take((size_t)M * H * 2);
  short* kbuf = (short*)take((size_t)M * H * 2);
  short* vtb  = (short*)take((size_t)M * H * 2);
  short* aob  = (short*)take((size_t)M * H * 2);
  short* fb   = (short*)take((size_t)M * PF * 2);
  short* wtq  = (short*)take((size_t)H * H * 2);
  short* wtk  = (short*)take((size_t)H * H * 2);
  short* wtv  = (short*)take((size_t)H * H * 2);
  short* wto  = (short*)take((size_t)H * H * 2);
  short* wt1  = (short*)take((size_t)H * PF * 2);
  short* wt2  = (short*)take((size_t)H * PF * 2);

  embed_kernel<<<M, 256, 0, stream>>>(src, tok, pos, xf, xb);

  for (int l = 0; l < L; l++) {
    wconv_kernel<<<(H / 64) * (H / 64), 256, 0, stream>>>(Wq + (size_t)l * H * H, wtq, H, H);
    wconv_kernel<<<(H / 64) * (H / 64), 256, 0, stream>>>(Wk + (size_t)l * H * H, wtk, H, H);
    wconv_kernel<<<(H / 64) * (H / 64), 256, 0, stream>>>(Wv + (size_t)l * H * H, wtv, H, H);
    wconv_kernel<<<(H / 64) * (H / 64), 256, 0, stream>>>(Wo + (size_t)l * H * H, wto, H, H);
    wconv_kernel<<<(H / 64) * (PF / 64), 256, 0, stream>>>(W1 + (size_t)l * H * PF, wt1, H, PF);
    wconv_kernel<<<(PF / 64) * (H / 64), 256, 0, stream>>>(W2 + (size_t)l * PF * H, wt2, PF, H);

    gemm_bf16<0><<<(M / 128) * (H / 128), 256, 0, stream>>>(xb, wtq, bq + (size_t)l * H, qb, H / 128, H);
    gemm_bf16<0><<<(M / 128) * (H / 128), 256, 0, stream>>>(xb, wtk, bk + (size_t)l * H, kbuf, H / 128, H);
    gemm_bf16<3><<<(M / 128) * (H / 128), 256, 0, stream>>>(xb, wtv, bv + (size_t)l * H, vtb, H / 128, H);
    attn_kernel<<<BB * NH * (S / 64), 256, 0, stream>>>(qb, kbuf, vtb, aob);
    gemm_bf16<2><<<(M / 128) * (H / 128), 256, 0, stream>>>(aob, wto, bo + (size_t)l * H, tmp, H / 128, H);
    ln_kernel<<<M, 256, 0, stream>>>(xf, tmp, g1 + (size_t)l * H, be1 + (size_t)l * H, xf, xb);
    gemm_bf16<1><<<(M / 128) * (PF / 128), 256, 0, stream>>>(xb, wt1, b1 + (size_t)l * PF, fb, PF / 128, H);
    gemm_bf16<2><<<(M / 128) * (H / 128), 256, 0, stream>>>(fb, wt2, b2 + (size_t)l * H, tmp, H / 128, PF);
    float* yf = (l == L - 1) ? (float*)d_out : xf;
    ln_kernel<<<M, 256, 0, stream>>>(xf, tmp, g2 + (size_t)l * H, be2 + (size_t)l * H, yf, xb);
  }
}